// Round 13
// baseline (47.383 us; speedup 1.0000x reference)
//
#include <hip/hip_runtime.h>

#define GB 64
#define GN 128
#define F_OBS 64
#define F_TOT 80
#define ISPLIT 32
#define IPB (GN / ISPLIT)   // 4 i-rows per block
#define REPS 8              // CALIBRATION: hot loop x8, outputs unchanged

// === R13 = CALIBRATION ROUND ===
// R10's kernel (best: 15.9us) with the MAC hot loop executed REPS=8 times:
//   dur ~= fixed + 8*t_hot   (R10: fixed + 1*t_hot = 15.9)
// -> solves the main-compute vs structural-tax split that 12 rounds of
// inference couldn't, AND lifts glcn_main above the 39us fill floor so its
// rocprof counters (VALUBusy / Occupancy / FETCH) become visible for the
// first time.
//  * zoff is laundered through an SGPR asm each rep -> the 64 s_load row
//    stream re-issues every rep (no cross-rep CSE).
//  * each rep's acc is kept alive via asm (rule #17: ablation-via-skip DCE)
//    so reps 0..6 aren't dead-code-eliminated.
//  * outputs bit-identical to R10: last rep's acc feeds the same epilogue.
__global__ __launch_bounds__(128, 4) void glcn_main(
    const float* __restrict__ h, const float* __restrict__ w,
    float* __restrict__ Aout, float* __restrict__ part) {
  const int blk = blockIdx.x;
  const int b  = blk >> 5;                    // / ISPLIT
  const int q  = blk & (ISPLIT - 1);          // i-split index
  const int is = q * IPB;                     // block-uniform
  const int j  = threadIdx.x;                 // 0..127

  const float* rowj = h + ((size_t)(b * GN + j)) * F_TOT;    // per-lane
  const float* rows = h + ((size_t)(b * GN + is)) * F_TOT;   // uniform->s_load

  // Own row prefetched once (outside the rep loop, as in R10).
  float4 hj[F_OBS / 4];
#pragma unroll
  for (int kq = 0; kq < F_OBS / 4; ++kq)
    hj[kq] = *reinterpret_cast<const float4*>(rowj + 4 * kq);

  float acc[IPB];
  for (int rep = 0; rep < REPS; ++rep) {
    int zoff = 0;
    asm volatile("" : "+s"(zoff));            // opaque 0: defeat load CSE
    const float* rowsr = rows + zoff;

    float a[IPB];
#pragma unroll
    for (int ii = 0; ii < IPB; ++ii) a[ii] = 0.f;

#pragma unroll
    for (int kq = 0; kq < F_OBS / 4; ++kq) {
      const float4 hv = hj[kq];
      const float4 wv = *reinterpret_cast<const float4*>(w + 4 * kq);
#pragma unroll
      for (int ii = 0; ii < IPB; ++ii) {
        const float* ri = rowsr + ii * F_TOT + 4 * kq;   // scalar dwordx4
        a[ii] = fmaf(wv.x, fabsf(hv.x - ri[0]), a[ii]);
        a[ii] = fmaf(wv.y, fabsf(hv.y - ri[1]), a[ii]);
        a[ii] = fmaf(wv.z, fabsf(hv.z - ri[2]), a[ii]);
        a[ii] = fmaf(wv.w, fabsf(hv.w - ri[3]), a[ii]);
      }
    }
    // Keep this rep's results live (prevent DCE of reps 0..REPS-2).
    asm volatile("" :: "v"(a[0]), "v"(a[1]), "v"(a[2]), "v"(a[3]));
#pragma unroll
    for (int ii = 0; ii < IPB; ++ii) acc[ii] = a[ii];
  }

  // Epilogue identical to R10.
  float logsum = 0.f;
  float* Abase = Aout + (size_t)b * GN * GN;
#pragma unroll
  for (int ii = 0; ii < IPB; ++ii) {
    const int i = is + ii;
    const float x = acc[ii];
    const float lt = -__logf(1.f + __expf(-fabsf(x)));
    float Aval = (x > 0.f) ? 1.f : 0.f;
    if (i == j) Aval = 1.f;     // diagonal: forced 1, excluded from log-sum
    else        logsum += lt;
    Abase[(size_t)i * GN + j] = Aval;   // lanes = consecutive j: coalesced
  }

#pragma unroll
  for (int off = 32; off > 0; off >>= 1)
    logsum += __shfl_down(logsum, off, 64);
  __shared__ float red[2];
  const int lane = threadIdx.x & 63;
  const int wid  = threadIdx.x >> 6;
  if (lane == 0) red[wid] = logsum;
  __syncthreads();
  if (threadIdx.x == 0) part[q * GB + b] = red[0] + red[1];
}

// probs[b] = sum of the 32 slice partials, fixed order, coalesced reads.
__global__ __launch_bounds__(64) void glcn_reduce(
    const float* __restrict__ part, float* __restrict__ probs) {
  const int b = threadIdx.x;
  float s = 0.f;
#pragma unroll
  for (int q = 0; q < ISPLIT; ++q) s += part[q * GB + b];
  probs[b] = s;
}

extern "C" void kernel_launch(void* const* d_in, const int* in_sizes, int n_in,
                              void* d_out, int out_size, void* d_ws, size_t ws_size,
                              hipStream_t stream) {
  const float* h = (const float*)d_in[0];   // [64,128,80] f32
  const float* w = (const float*)d_in[1];   // [64,1] f32
  float* Aout  = (float*)d_out;                       // [64,128,128]
  float* probs = Aout + (size_t)GB * GN * GN;         // [64]
  float* part  = (float*)d_ws;                        // ISPLIT*GB floats

  glcn_main<<<GB * ISPLIT, 128, 0, stream>>>(h, w, Aout, part);
  glcn_reduce<<<1, 64, 0, stream>>>(part, probs);
}

// Round 14
// 14.474 us; speedup vs baseline: 3.2736x; 3.2736x over previous
//
#include <hip/hip_runtime.h>

#define GB 64
#define GN 128
#define F_OBS 64
#define F_TOT 80
#define ISPLIT 32
#define IPB (GN / ISPLIT)   // 4 i-rows per block

// R10's kernel (best: 15.9us) + XCD-aware block remap (T1 adapted).
// R13 calibration: t_hot=4.5us, fixed=11.4us, and FETCH showed ~2.5MB of
// HBM traffic PER PASS over h (h itself is only 2.6MB): consecutive blk
// round-robin the 8 XCDs, so every XCD streamed ~all of h through its
// private 4MB L2 (8 x 2.6 = 21MB = R13's FETCH). Remap so each XCD owns 8
// batches (320KB of h -> L2-resident): with hardware xcd = blk%8,
//   b = (blk&7) + 8*((blk>>3)&7),  q = blk>>6   (bijective over 2048)
// -> cold-miss ramp and steady HBM re-reads become L2 hits.
//
// Standing lessons: two plain dispatches beat every merged variant (R5/R7/
// R11); no cross-block ordering (R2: 7x); no atomics/memset (R5); partner
// rows on the scalar pipe (R7); ISPLIT=32 sweet spot (R8/R9); own-row
// prefetched once (R10); LDS staging loses to s_load stream (R12).
__global__ __launch_bounds__(128, 4) void glcn_main(
    const float* __restrict__ h, const float* __restrict__ w,
    float* __restrict__ Aout, float* __restrict__ part) {
  const int blk = blockIdx.x;
  const int b  = (blk & 7) + 8 * ((blk >> 3) & 7);   // batch: XCD-clustered
  const int q  = blk >> 6;                           // i-split 0..31
  const int is = q * IPB;                            // block-uniform
  const int j  = threadIdx.x;                        // 0..127

  const float* rowj = h + ((size_t)(b * GN + j)) * F_TOT;    // per-lane
  const float* rows = h + ((size_t)(b * GN + is)) * F_TOT;   // uniform->s_load

  // Own row prefetched once: 16 independent float4 loads, one drain.
  float4 hj[F_OBS / 4];
#pragma unroll
  for (int kq = 0; kq < F_OBS / 4; ++kq)
    hj[kq] = *reinterpret_cast<const float4*>(rowj + 4 * kq);

  float acc[IPB];
#pragma unroll
  for (int ii = 0; ii < IPB; ++ii) acc[ii] = 0.f;

#pragma unroll
  for (int kq = 0; kq < F_OBS / 4; ++kq) {
    const float4 hv = hj[kq];
    const float4 wv = *reinterpret_cast<const float4*>(w + 4 * kq);  // scalar
#pragma unroll
    for (int ii = 0; ii < IPB; ++ii) {
      const float* ri = rows + ii * F_TOT + 4 * kq;   // scalar dwordx4
      acc[ii] = fmaf(wv.x, fabsf(hv.x - ri[0]), acc[ii]);
      acc[ii] = fmaf(wv.y, fabsf(hv.y - ri[1]), acc[ii]);
      acc[ii] = fmaf(wv.z, fabsf(hv.z - ri[2]), acc[ii]);
      acc[ii] = fmaf(wv.w, fabsf(hv.w - ri[3]), acc[ii]);
    }
  }

  // Epilogue. sigmoid(x)>0.5 <=> x>0; selected = A?y:(1-y) = sigmoid(|x|);
  // log(sigmoid(|x|)+1e-8) = -log(1+exp(-|x|)) + O(2e-8).
  float logsum = 0.f;
  float* Abase = Aout + (size_t)b * GN * GN;
#pragma unroll
  for (int ii = 0; ii < IPB; ++ii) {
    const int i = is + ii;
    const float x = acc[ii];
    const float lt = -__logf(1.f + __expf(-fabsf(x)));
    float Aval = (x > 0.f) ? 1.f : 0.f;
    if (i == j) Aval = 1.f;     // diagonal: forced 1, excluded from log-sum
    else        logsum += lt;
    Abase[(size_t)i * GN + j] = Aval;   // lanes = consecutive j: coalesced
  }

  // Deterministic intra-block reduction (fixed shuffle-tree order).
#pragma unroll
  for (int off = 32; off > 0; off >>= 1)
    logsum += __shfl_down(logsum, off, 64);
  __shared__ float red[2];
  const int lane = threadIdx.x & 63;
  const int wid  = threadIdx.x >> 6;
  if (lane == 0) red[wid] = logsum;
  __syncthreads();
  // Transposed layout: consecutive b in consecutive addresses per q-slice.
  if (threadIdx.x == 0) part[q * GB + b] = red[0] + red[1];
}

// probs[b] = sum of the 32 slice partials, fixed order; each of the 32 loads
// is fully coalesced across the 64 threads (part is [ISPLIT][GB]).
__global__ __launch_bounds__(64) void glcn_reduce(
    const float* __restrict__ part, float* __restrict__ probs) {
  const int b = threadIdx.x;
  float s = 0.f;
#pragma unroll
  for (int q = 0; q < ISPLIT; ++q) s += part[q * GB + b];
  probs[b] = s;
}

extern "C" void kernel_launch(void* const* d_in, const int* in_sizes, int n_in,
                              void* d_out, int out_size, void* d_ws, size_t ws_size,
                              hipStream_t stream) {
  const float* h = (const float*)d_in[0];   // [64,128,80] f32
  const float* w = (const float*)d_in[1];   // [64,1] f32
  float* Aout  = (float*)d_out;                       // [64,128,128]
  float* probs = Aout + (size_t)GB * GN * GN;         // [64]
  float* part  = (float*)d_ws;                        // ISPLIT*GB floats

  glcn_main<<<GB * ISPLIT, 128, 0, stream>>>(h, w, Aout, part);
  glcn_reduce<<<1, 64, 0, stream>>>(part, probs);
}